// Round 3
// baseline (231.097 us; speedup 1.0000x reference)
//
#include <hip/hip_runtime.h>

#define DIM 256  // 2^8 amplitudes

typedef float v2f __attribute__((ext_vector_type(2)));

// 5 layer matrices, 4x4 complex each, row-major M[r*4+c]
__device__ float2 g_M[5 * 16];

__device__ inline float2 cmulc(float2 a, float2 b) {
    return make_float2(a.x * b.x - a.y * b.y, a.x * b.y + a.y * b.x);
}
__device__ inline float2 caddc(float2 a, float2 b) {
    return make_float2(a.x + b.x, a.y + b.y);
}

// ---------------- setup: build the 5 SU(4) gate matrices ----------------

__device__ void mat_u3(float t, float p, float l, float2* U) {
    float s, c;
    sincosf(0.5f * t, &s, &c);
    float sp, cp, sl, cl, spl, cpl;
    sincosf(p, &sp, &cp);
    sincosf(l, &sl, &cl);
    sincosf(p + l, &spl, &cpl);
    U[0] = make_float2(c, 0.f);
    U[1] = make_float2(-cl * s, -sl * s);
    U[2] = make_float2(cp * s, sp * s);
    U[3] = make_float2(cpl * c, spl * c);
}
__device__ void mat_ry(float t, float2* U) {
    float s, c;
    sincosf(0.5f * t, &s, &c);
    U[0] = make_float2(c, 0.f); U[1] = make_float2(-s, 0.f);
    U[2] = make_float2(s, 0.f); U[3] = make_float2(c, 0.f);
}
__device__ void mat_rz(float t, float2* U) {
    float s, c;
    sincosf(0.5f * t, &s, &c);
    U[0] = make_float2(c, -s); U[1] = make_float2(0.f, 0.f);
    U[2] = make_float2(0.f, 0.f); U[3] = make_float2(c, s);
}
__device__ void mat_I2(float2* U) {
    U[0] = make_float2(1.f, 0.f); U[1] = make_float2(0.f, 0.f);
    U[2] = make_float2(0.f, 0.f); U[3] = make_float2(1.f, 0.f);
}
__device__ void kron4(const float2* A, const float2* B, float2* K) {
    for (int i0 = 0; i0 < 2; ++i0)
        for (int i1 = 0; i1 < 2; ++i1)
            for (int j0 = 0; j0 < 2; ++j0)
                for (int j1 = 0; j1 < 2; ++j1)
                    K[(2 * i0 + i1) * 4 + (2 * j0 + j1)] = cmulc(A[i0 * 2 + j0], B[i1 * 2 + j1]);
}
__device__ void mm4(const float2* A, const float2* B, float2* C) {
    for (int r = 0; r < 4; ++r)
        for (int c = 0; c < 4; ++c) {
            float2 acc = make_float2(0.f, 0.f);
            for (int k = 0; k < 4; ++k) acc = caddc(acc, cmulc(A[r * 4 + k], B[k * 4 + c]));
            C[r * 4 + c] = acc;
        }
}
__device__ void swap_rows(float2* M, int r1, int r2) {
    for (int c = 0; c < 4; ++c) {
        float2 t = M[r1 * 4 + c]; M[r1 * 4 + c] = M[r2 * 4 + c]; M[r2 * 4 + c] = t;
    }
}

__global__ void qsvdd_setup(const float* __restrict__ w) {
    int l = threadIdx.x;
    if (l >= 5) return;
    const float* p = w + l * 15;
    float2 A[4], Bm[4], K[16], M[16], T[16];
    mat_u3(p[0], p[1], p[2], A);
    mat_u3(p[3], p[4], p[5], Bm);
    kron4(A, Bm, M);
    swap_rows(M, 2, 3);                       // CNOT01 @ M
    mat_ry(p[6], A); mat_rz(p[7], Bm);
    kron4(A, Bm, K); mm4(K, M, T);
    swap_rows(T, 1, 3);                       // CNOT10 @ M
    mat_ry(p[8], A); mat_I2(Bm);
    kron4(A, Bm, K); mm4(K, T, M);
    swap_rows(M, 2, 3);                       // CNOT01 @ M
    mat_u3(p[9], p[10], p[11], A);
    mat_u3(p[12], p[13], p[14], Bm);
    kron4(A, Bm, K); mm4(K, M, T);
    for (int i = 0; i < 16; ++i) g_M[l * 16 + i] = T[i];
}

// ---------------- main: register-resident statevector, packed-FP32 gates ----------------
//
// State: 4 complex amplitudes/lane as v2f (re,im) pairs; 2 local bits in the
// register index, 6 bits in the lane id. Gates = 4x4 complex matvec done with
// v_pk_fma_f32 (packed fp32, 2 instr per complex MAC; broadcast/swap/negate
// via op_sel/neg_lo). Bit swaps (local<->lane) via ds_bpermute. No LDS tiles,
// no barriers.

__device__ __forceinline__ v2f mk2(float a, float b) {
    v2f r; r.x = a; r.y = b; return r;
}

// acc = m * v (complex), packed
__device__ __forceinline__ void cmul_pk(v2f& acc, v2f m, v2f v) {
    asm("v_pk_mul_f32 %0, %1, %2 op_sel:[0,0] op_sel_hi:[0,1]\n\t"
        "v_pk_fma_f32 %0, %1, %2, %0 op_sel:[1,1,0] op_sel_hi:[1,0,1] neg_lo:[1,0,0]"
        : "=&v"(acc) : "v"(m), "v"(v));
}
// acc += m * v (complex), packed
__device__ __forceinline__ void cmad_pk(v2f& acc, v2f m, v2f v) {
    asm("v_pk_fma_f32 %0, %1, %2, %0 op_sel:[0,0,0] op_sel_hi:[0,1,1]\n\t"
        "v_pk_fma_f32 %0, %1, %2, %0 op_sel:[1,1,0] op_sel_hi:[1,0,1] neg_lo:[1,0,0]"
        : "+v"(acc) : "v"(m), "v"(v));
}

// 4x4 complex matvec; IP = local slot of first tensor factor, IQ = second.
template <int IP, int IQ>
__device__ __forceinline__ void gate4(v2f* v, const v2f* M) {
    constexpr int mp = 1 << IP, mq = 1 << IQ;
    const v2f a0 = v[0], a1 = v[mq], a2 = v[mp], a3 = v[mp | mq];
    v2f n0, n1, n2, n3;
    cmul_pk(n0, M[0],  a0); cmad_pk(n0, M[1],  a1); cmad_pk(n0, M[2],  a2); cmad_pk(n0, M[3],  a3);
    cmul_pk(n1, M[4],  a0); cmad_pk(n1, M[5],  a1); cmad_pk(n1, M[6],  a2); cmad_pk(n1, M[7],  a3);
    cmul_pk(n2, M[8],  a0); cmad_pk(n2, M[9],  a1); cmad_pk(n2, M[10], a2); cmad_pk(n2, M[11], a3);
    cmul_pk(n3, M[12], a0); cmad_pk(n3, M[13], a1); cmad_pk(n3, M[14], a2); cmad_pk(n3, M[15], a3);
    v[0] = n0; v[mq] = n1; v[mp] = n2; v[mp | mq] = n3;
}

__device__ __forceinline__ v2f bperm2(int ba, v2f s) {
    v2f r;
    r.x = __int_as_float(__builtin_amdgcn_ds_bpermute(ba, __float_as_int(s.x)));
    r.y = __int_as_float(__builtin_amdgcn_ds_bpermute(ba, __float_as_int(s.y)));
    return r;
}

// swap local (register) bit R with a lane bit; pb = own lane bit, ba = bpermute
// byte-address of partner lane (= (lane ^ mask) << 2).
template <int R>
__device__ __forceinline__ void bswap(v2f* v, bool pb, int ba) {
    constexpr int m = 1 << R;
#pragma unroll
    for (int j = 0; j < 4; ++j) {
        if (j & m) continue;
        const int j1 = j | m;
        v2f s = pb ? v[j] : v[j1];
        v2f r = bperm2(ba, s);
        v[j] = pb ? r : v[j];
        v[j1] = pb ? v[j1] : r;
    }
}

__global__ __launch_bounds__(256) void qsvdd_main(const float* __restrict__ x,
                                                  float* __restrict__ out) {
    const int lane = threadIdx.x & 63;
    const long e = (long)blockIdx.x * 4 + (threadIdx.x >> 6);

    const int ba0 = ((lane ^ 1) << 2), ba1 = ((lane ^ 2) << 2), ba2 = ((lane ^ 4) << 2);
    const int ba3 = ((lane ^ 8) << 2), ba4 = ((lane ^ 16) << 2), ba5 = ((lane ^ 32) << 2);
    const bool p0 = lane & 1, p1 = lane & 2, p2 = lane & 4;
    const bool p3 = lane & 8, p4 = lane & 16, p5 = lane & 32;

    // ---- amplitude embedding: a = lane*4 + j (local bits = logical 1:0) ----
    float4 xv = *reinterpret_cast<const float4*>(x + (e << 8) + (lane << 2));
    float ss = xv.x * xv.x + xv.y * xv.y + xv.z * xv.z + xv.w * xv.w;
#pragma unroll
    for (int off = 32; off; off >>= 1) ss += __shfl_xor(ss, off, 64);
    const float inv = rsqrtf(ss);
    v2f v[4];
    v[0] = mk2(xv.x * inv, 0.f);
    v[1] = mk2(xv.y * inv, 0.f);
    v[2] = mk2(xv.z * inv, 0.f);
    v[3] = mk2(xv.w * inv, 0.f);

    v2f Mm[16];
#define LOADM(L)                                                              \
    {                                                                         \
        const v2f* gm = reinterpret_cast<const v2f*>(g_M) + (L) * 16;         \
        _Pragma("unroll") for (int i = 0; i < 16; ++i) Mm[i] = gm[i];         \
    }

    // ---- hand-derived schedule (validated in R1/R2) ----
    LOADM(0);
    // A1: (1,0),(3,2),(5,4),(7,6)
    gate4<1, 0>(v, Mm);                           // (1,0)  s=(0,1)
    bswap<0>(v, p0, ba0); bswap<1>(v, p1, ba1);   // s=(2,3)
    gate4<1, 0>(v, Mm);                           // (3,2)
    bswap<0>(v, p2, ba2); bswap<1>(v, p3, ba3);   // s=(4,5)
    gate4<1, 0>(v, Mm);                           // (5,4)
    bswap<0>(v, p4, ba4); bswap<1>(v, p5, ba5);   // s=(6,7)
    gate4<1, 0>(v, Mm);                           // (7,6)
    // B1: (6,5),(4,3),(2,1),(0,7)
    bswap<1>(v, p5, ba5);                         // s=(6,5)
    gate4<0, 1>(v, Mm);                           // (6,5)
    bswap<0>(v, p4, ba4); bswap<1>(v, p3, ba3);   // s=(4,3)
    gate4<0, 1>(v, Mm);                           // (4,3)
    bswap<0>(v, p2, ba2); bswap<1>(v, p1, ba1);   // s=(2,1)
    gate4<0, 1>(v, Mm);                           // (2,1)
    bswap<0>(v, p0, ba0); bswap<1>(v, p5, ba5);   // s=(0,7)
    gate4<0, 1>(v, Mm);                           // (0,7)
    LOADM(1);
    // A2
    bswap<1>(v, p5, ba5);                         // s=(0,1)
    gate4<1, 0>(v, Mm);                           // (1,0)
    bswap<0>(v, p0, ba0); bswap<1>(v, p1, ba1);   // s=(2,3)
    gate4<1, 0>(v, Mm);                           // (3,2)
    bswap<0>(v, p2, ba2); bswap<1>(v, p3, ba3);   // s=(4,5)
    gate4<1, 0>(v, Mm);                           // (5,4)
    bswap<0>(v, p4, ba4); bswap<1>(v, p5, ba5);   // s=(6,7)
    gate4<1, 0>(v, Mm);                           // (7,6)
    // B2
    bswap<1>(v, p5, ba5);                         // s=(6,5)
    gate4<0, 1>(v, Mm);                           // (6,5)
    bswap<0>(v, p4, ba4); bswap<1>(v, p3, ba3);   // s=(4,3)
    gate4<0, 1>(v, Mm);                           // (4,3)
    bswap<0>(v, p2, ba2); bswap<1>(v, p1, ba1);   // s=(2,1)
    gate4<0, 1>(v, Mm);                           // (2,1)
    bswap<0>(v, p0, ba0); bswap<1>(v, p5, ba5);   // s=(0,7)
    gate4<0, 1>(v, Mm);                           // (0,7)
    LOADM(2);
    // A3: (1,7),(5,3)
    bswap<0>(v, p5, ba5);                         // s=(1,7)
    gate4<0, 1>(v, Mm);                           // (1,7)
    bswap<0>(v, p1, ba1); bswap<1>(v, p3, ba3);   // s=(3,5)
    gate4<1, 0>(v, Mm);                           // (5,3)
    // B3: (7,5),(3,1)
    bswap<0>(v, p3, ba3);                         // s=(7,5)
    gate4<0, 1>(v, Mm);                           // (7,5)
    bswap<0>(v, p3, ba3); bswap<1>(v, p1, ba1);   // s=(3,1)
    gate4<0, 1>(v, Mm);                           // (3,1)
    LOADM(3);
    // A4: (1,7),(5,3)
    bswap<0>(v, p3, ba3);                         // s=(7,1)
    gate4<1, 0>(v, Mm);                           // (1,7)
    bswap<0>(v, p3, ba3); bswap<1>(v, p1, ba1);   // s=(3,5)
    gate4<1, 0>(v, Mm);                           // (5,3)
    // B4
    bswap<0>(v, p3, ba3);                         // s=(7,5)
    gate4<0, 1>(v, Mm);                           // (7,5)
    bswap<0>(v, p3, ba3); bswap<1>(v, p1, ba1);   // s=(3,1)
    gate4<0, 1>(v, Mm);                           // (3,1)
    LOADM(4);
    // L3: (5,1)
    bswap<0>(v, p1, ba1);                         // s=(5,1)
    gate4<0, 1>(v, Mm);                           // (5,1)

    // ---- expvals: bit 5 (wire 2) at slot 0, bit 1 (wire 6) at slot 1 ----
    float acc[6];
    {
        const v2f a = v[0], b = v[1], c = v[2], d = v[3];
        acc[0] = (a.x * b.x + a.y * b.y) + (c.x * d.x + c.y * d.y);
        acc[1] = (a.x * b.y - a.y * b.x) + (c.x * d.y - c.y * d.x);
        acc[2] = (a.x * a.x + a.y * a.y) - (b.x * b.x + b.y * b.y)
               + (c.x * c.x + c.y * c.y) - (d.x * d.x + d.y * d.y);
        acc[3] = (a.x * c.x + a.y * c.y) + (b.x * d.x + b.y * d.y);
        acc[4] = (a.x * c.y - a.y * c.x) + (b.x * d.y - b.y * d.x);
        acc[5] = (a.x * a.x + a.y * a.y) - (c.x * c.x + c.y * c.y)
               + (b.x * b.x + b.y * b.y) - (d.x * d.x + d.y * d.y);
    }
    acc[0] *= 2.f; acc[1] *= 2.f; acc[3] *= 2.f; acc[4] *= 2.f;
#pragma unroll
    for (int k = 0; k < 6; ++k) {
#pragma unroll
        for (int off = 32; off; off >>= 1) acc[k] += __shfl_xor(acc[k], off, 64);
    }
    if (lane == 0) {
        float* o = out + e * 6;
        o[0] = acc[0]; o[1] = acc[1]; o[2] = acc[2];
        o[3] = acc[3]; o[4] = acc[4]; o[5] = acc[5];
    }
}

extern "C" void kernel_launch(void* const* d_in, const int* in_sizes, int n_in,
                              void* d_out, int out_size, void* d_ws, size_t ws_size,
                              hipStream_t stream) {
    const float* x = (const float*)d_in[0];
    const float* w = (const float*)d_in[1];
    float* out = (float*)d_out;
    const int B = in_sizes[0] / DIM;  // 32768

    hipLaunchKernelGGL(qsvdd_setup, dim3(1), dim3(64), 0, stream, w);
    hipLaunchKernelGGL(qsvdd_main, dim3(B / 4), dim3(256), 0, stream, x, out);
}

// Round 4
// 132.120 us; speedup vs baseline: 1.7491x; 1.7491x over previous
//
#include <hip/hip_runtime.h>

#define DIM 256  // 2^8 amplitudes

// 5 layer matrices, 4x4 complex each, row-major M[r*4+c]
__device__ float2 g_M[5 * 16];

__device__ inline float2 cmulc(float2 a, float2 b) {
    return make_float2(a.x * b.x - a.y * b.y, a.x * b.y + a.y * b.x);
}
__device__ inline float2 caddc(float2 a, float2 b) {
    return make_float2(a.x + b.x, a.y + b.y);
}

// ---------------- setup: build the 5 SU(4) gate matrices ----------------

__device__ void mat_u3(float t, float p, float l, float2* U) {
    float s, c;
    sincosf(0.5f * t, &s, &c);
    float sp, cp, sl, cl, spl, cpl;
    sincosf(p, &sp, &cp);
    sincosf(l, &sl, &cl);
    sincosf(p + l, &spl, &cpl);
    U[0] = make_float2(c, 0.f);
    U[1] = make_float2(-cl * s, -sl * s);
    U[2] = make_float2(cp * s, sp * s);
    U[3] = make_float2(cpl * c, spl * c);
}
__device__ void mat_ry(float t, float2* U) {
    float s, c;
    sincosf(0.5f * t, &s, &c);
    U[0] = make_float2(c, 0.f); U[1] = make_float2(-s, 0.f);
    U[2] = make_float2(s, 0.f); U[3] = make_float2(c, 0.f);
}
__device__ void mat_rz(float t, float2* U) {
    float s, c;
    sincosf(0.5f * t, &s, &c);
    U[0] = make_float2(c, -s); U[1] = make_float2(0.f, 0.f);
    U[2] = make_float2(0.f, 0.f); U[3] = make_float2(c, s);
}
__device__ void mat_I2(float2* U) {
    U[0] = make_float2(1.f, 0.f); U[1] = make_float2(0.f, 0.f);
    U[2] = make_float2(0.f, 0.f); U[3] = make_float2(1.f, 0.f);
}
__device__ void kron4(const float2* A, const float2* B, float2* K) {
    for (int i0 = 0; i0 < 2; ++i0)
        for (int i1 = 0; i1 < 2; ++i1)
            for (int j0 = 0; j0 < 2; ++j0)
                for (int j1 = 0; j1 < 2; ++j1)
                    K[(2 * i0 + i1) * 4 + (2 * j0 + j1)] = cmulc(A[i0 * 2 + j0], B[i1 * 2 + j1]);
}
__device__ void mm4(const float2* A, const float2* B, float2* C) {
    for (int r = 0; r < 4; ++r)
        for (int c = 0; c < 4; ++c) {
            float2 acc = make_float2(0.f, 0.f);
            for (int k = 0; k < 4; ++k) acc = caddc(acc, cmulc(A[r * 4 + k], B[k * 4 + c]));
            C[r * 4 + c] = acc;
        }
}
__device__ void swap_rows(float2* M, int r1, int r2) {
    for (int c = 0; c < 4; ++c) {
        float2 t = M[r1 * 4 + c]; M[r1 * 4 + c] = M[r2 * 4 + c]; M[r2 * 4 + c] = t;
    }
}

__global__ void qsvdd_setup(const float* __restrict__ w) {
    int l = threadIdx.x;
    if (l >= 5) return;
    const float* p = w + l * 15;
    float2 A[4], Bm[4], K[16], M[16], T[16];
    mat_u3(p[0], p[1], p[2], A);
    mat_u3(p[3], p[4], p[5], Bm);
    kron4(A, Bm, M);
    swap_rows(M, 2, 3);                       // CNOT01 @ M
    mat_ry(p[6], A); mat_rz(p[7], Bm);
    kron4(A, Bm, K); mm4(K, M, T);
    swap_rows(T, 1, 3);                       // CNOT10 @ M
    mat_ry(p[8], A); mat_I2(Bm);
    kron4(A, Bm, K); mm4(K, T, M);
    swap_rows(M, 2, 3);                       // CNOT01 @ M
    mat_u3(p[9], p[10], p[11], A);
    mat_u3(p[12], p[13], p[14], Bm);
    kron4(A, Bm, K); mm4(K, M, T);
    for (int i = 0; i < 16; ++i) g_M[l * 16 + i] = T[i];
}

// ---------------- main: register-resident statevector, permlane swaps ----------------
//
// State: 4 complex amps/lane (float2 v[4]); 2 local bits in the register index,
// 6 in the lane id. Gates: scalar-FMA 4x4 complex matvec, matrix in SGPRs
// (uniform loads). Local<->lane-bit exchanges:
//  - lane bit 5: v_permlane32_swap_b32 (1 instr per reg-pair component)
//  - lane bit 4: v_permlane16_swap_b32
//  - lane bits 0-3: first a lane-lane bit swap (pure permutation via
//    ds_bpermute, zero VALU, precomputed addresses), routing through bit 5.
// Hand-derived 25-gate schedule with full position bookkeeping (verified).

__device__ __forceinline__ void cmadf(float2& a, float mx, float my, float2 v) {
    a.x = fmaf(mx, v.x, a.x);
    a.x = fmaf(-my, v.y, a.x);
    a.y = fmaf(mx, v.y, a.y);
    a.y = fmaf(my, v.x, a.y);
}
__device__ __forceinline__ float2 cmulf(float mx, float my, float2 v) {
    float2 r;
    r.x = mx * v.x; r.x = fmaf(-my, v.y, r.x);
    r.y = mx * v.y; r.y = fmaf(my, v.x, r.y);
    return r;
}

// 4x4 complex matvec; IP = local slot of first tensor factor, IQ = second.
template <int IP, int IQ>
__device__ __forceinline__ void gate4(float2* v, const float2* M) {
    constexpr int mp = 1 << IP, mq = 1 << IQ;
    const float2 a0 = v[0], a1 = v[mq], a2 = v[mp], a3 = v[mp | mq];
    float2 n0 = cmulf(M[0].x,  M[0].y,  a0);
    cmadf(n0, M[1].x,  M[1].y,  a1); cmadf(n0, M[2].x,  M[2].y,  a2); cmadf(n0, M[3].x,  M[3].y,  a3);
    float2 n1 = cmulf(M[4].x,  M[4].y,  a0);
    cmadf(n1, M[5].x,  M[5].y,  a1); cmadf(n1, M[6].x,  M[6].y,  a2); cmadf(n1, M[7].x,  M[7].y,  a3);
    float2 n2 = cmulf(M[8].x,  M[8].y,  a0);
    cmadf(n2, M[9].x,  M[9].y,  a1); cmadf(n2, M[10].x, M[10].y, a2); cmadf(n2, M[11].x, M[11].y, a3);
    float2 n3 = cmulf(M[12].x, M[12].y, a0);
    cmadf(n3, M[13].x, M[13].y, a1); cmadf(n3, M[14].x, M[14].y, a2); cmadf(n3, M[15].x, M[15].y, a3);
    v[0] = n0; v[mq] = n1; v[mp] = n2; v[mp | mq] = n3;
}

// vdst = lower register of the pair (holds local-bit=0 amps)
__device__ __forceinline__ void plsw32(float& a, float& b) {
    asm("v_permlane32_swap_b32 %0, %1" : "+v"(a), "+v"(b));
}
__device__ __forceinline__ void plsw16(float& a, float& b) {
    asm("v_permlane16_swap_b32 %0, %1" : "+v"(a), "+v"(b));
}

// exchange local slot R with lane bit 5
template <int R>
__device__ __forceinline__ void pl32(float2* v) {
    if constexpr (R == 0) {
        plsw32(v[0].x, v[1].x); plsw32(v[0].y, v[1].y);
        plsw32(v[2].x, v[3].x); plsw32(v[2].y, v[3].y);
    } else {
        plsw32(v[0].x, v[2].x); plsw32(v[0].y, v[2].y);
        plsw32(v[1].x, v[3].x); plsw32(v[1].y, v[3].y);
    }
}
// exchange local slot R with lane bit 4
template <int R>
__device__ __forceinline__ void pl16(float2* v) {
    if constexpr (R == 0) {
        plsw16(v[0].x, v[1].x); plsw16(v[0].y, v[1].y);
        plsw16(v[2].x, v[3].x); plsw16(v[2].y, v[3].y);
    } else {
        plsw16(v[0].x, v[2].x); plsw16(v[0].y, v[2].y);
        plsw16(v[1].x, v[3].x); plsw16(v[1].y, v[3].y);
    }
}

// lane-lane swap of lane bits K and 5 (pure permutation, no VALU selects)
template <int K>
__device__ __forceinline__ void lswap(float2* v, const int* bsw) {
    const int a = bsw[K];
#pragma unroll
    for (int j = 0; j < 4; ++j) {
        v[j].x = __int_as_float(__builtin_amdgcn_ds_bpermute(a, __float_as_int(v[j].x)));
        v[j].y = __int_as_float(__builtin_amdgcn_ds_bpermute(a, __float_as_int(v[j].y)));
    }
}

__global__ __launch_bounds__(256) void qsvdd_main(const float* __restrict__ x,
                                                  float* __restrict__ out) {
    const int lane = threadIdx.x & 63;
    const long e = (long)blockIdx.x * 4 + (threadIdx.x >> 6);

    // bpermute addresses for lane-bit swaps (k <-> 5), k = 0..3
    int bsw[4];
#pragma unroll
    for (int k = 0; k < 4; ++k) {
        const int d = ((lane >> k) ^ (lane >> 5)) & 1;
        const int m = d ? ((1 << k) | 32) : 0;
        bsw[k] = (lane ^ m) << 2;
    }

    // ---- amplitude embedding: a = lane*4 + j (local bits = logical 1:0) ----
    float4 xv = *reinterpret_cast<const float4*>(x + (e << 8) + (lane << 2));
    float ss = xv.x * xv.x + xv.y * xv.y + xv.z * xv.z + xv.w * xv.w;
#pragma unroll
    for (int off = 32; off; off >>= 1) ss += __shfl_xor(ss, off, 64);
    const float inv = rsqrtf(ss);
    float2 v[4];
    v[0] = make_float2(xv.x * inv, 0.f);
    v[1] = make_float2(xv.y * inv, 0.f);
    v[2] = make_float2(xv.z * inv, 0.f);
    v[3] = make_float2(xv.w * inv, 0.f);

    float2 Mm[16];
#define LOADM(L)                                                      \
    {                                                                 \
        _Pragma("unroll") for (int i = 0; i < 16; ++i)                \
            Mm[i] = g_M[(L) * 16 + i];                                \
    }

    // ---- schedule (S = local slots, P = lane-bit positions, verified) ----
    LOADM(0);
    // A1: gates on bits (1,0),(3,2),(5,4),(7,6)       init S=(0,1) P=(2,3,4,5,6,7)
    gate4<1, 0>(v, Mm);                                       // (1,0)
    lswap<0>(v, bsw); pl32<0>(v);                             // S0=2
    lswap<1>(v, bsw); pl32<1>(v);                             // S1=3
    gate4<1, 0>(v, Mm);                                       // (3,2)
    lswap<2>(v, bsw); pl32<0>(v);                             // S0=4
    lswap<3>(v, bsw); pl32<1>(v);                             // S1=5
    gate4<1, 0>(v, Mm);                                       // (5,4)
    lswap<0>(v, bsw); pl32<0>(v);                             // S0=7
    pl16<1>(v);                                               // S1=6
    gate4<0, 1>(v, Mm);                                       // (7,6)
    // B1: (6,5),(4,3),(2,1),(0,7)                     P=(3,0,1,2,5,4)
    pl16<0>(v);                                               // S0=5
    gate4<1, 0>(v, Mm);                                       // (6,5)
    pl32<0>(v);                                               // S0=4
    lswap<0>(v, bsw); pl32<1>(v);                             // S1=3
    gate4<0, 1>(v, Mm);                                       // (4,3)
    lswap<3>(v, bsw); pl32<0>(v);                             // S0=2
    lswap<2>(v, bsw); pl32<1>(v);                             // S1=1
    gate4<0, 1>(v, Mm);                                       // (2,1)
    lswap<1>(v, bsw); pl32<0>(v);                             // S0=0
    pl16<1>(v);                                               // S1=7
    gate4<0, 1>(v, Mm);                                       // (0,7)
    LOADM(1);
    // A2: (1,0),(3,2),(5,4),(7,6)                     P=(5,3,4,6,1,2)
    pl16<1>(v);                                               // S1=1
    gate4<1, 0>(v, Mm);                                       // (1,0)
    pl32<0>(v);                                               // S0=2
    lswap<1>(v, bsw); pl32<1>(v);                             // S1=3
    gate4<1, 0>(v, Mm);                                       // (3,2)
    lswap<0>(v, bsw); pl32<0>(v);                             // S0=5
    lswap<2>(v, bsw); pl32<1>(v);                             // S1=4
    gate4<0, 1>(v, Mm);                                       // (5,4)
    pl16<0>(v);                                               // S0=7
    lswap<3>(v, bsw); pl32<1>(v);                             // S1=6
    gate4<0, 1>(v, Mm);                                       // (7,6)
    // B2: (6,5),(4,3),(2,1),(0,7)                     P=(1,0,2,3,5,4)
    pl16<0>(v);                                               // S0=5
    gate4<1, 0>(v, Mm);                                       // (6,5)
    pl32<0>(v);                                               // S0=4
    lswap<3>(v, bsw); pl32<1>(v);                             // S1=3
    gate4<0, 1>(v, Mm);                                       // (4,3)
    lswap<2>(v, bsw); pl32<0>(v);                             // S0=2
    lswap<0>(v, bsw); pl32<1>(v);                             // S1=1
    gate4<0, 1>(v, Mm);                                       // (2,1)
    lswap<1>(v, bsw); pl32<0>(v);                             // S0=0
    pl16<1>(v);                                               // S1=7
    gate4<0, 1>(v, Mm);                                       // (0,7)
    LOADM(2);
    // A3: (5,3),(1,7)                                 P=(4,3,6,5,1,2)
    lswap<3>(v, bsw); pl32<0>(v);                             // S0=5
    lswap<1>(v, bsw); pl32<1>(v);                             // S1=3
    gate4<0, 1>(v, Mm);                                       // (5,3)
    pl32<0>(v);                                               // S0=7
    pl16<1>(v);                                               // S1=1
    gate4<1, 0>(v, Mm);                                       // (1,7)
    // B3: (7,5),(3,1)                                 P=(4,0,6,2,3,5)
    pl32<1>(v);                                               // S1=5
    gate4<0, 1>(v, Mm);                                       // (7,5)
    pl32<0>(v);                                               // S0=1
    pl16<1>(v);                                               // S1=3
    gate4<1, 0>(v, Mm);                                       // (3,1)
    LOADM(3);
    // A4: (5,3),(1,7)                                 P=(4,0,6,2,5,7)
    pl16<0>(v);                                               // S0=5
    gate4<0, 1>(v, Mm);                                       // (5,3)
    pl16<0>(v);                                               // S0=1
    pl32<1>(v);                                               // S1=7
    gate4<0, 1>(v, Mm);                                       // (1,7)
    // B4: (7,5),(3,1)                                 P=(4,0,6,2,5,3)
    pl16<0>(v);                                               // S0=5
    gate4<1, 0>(v, Mm);                                       // (7,5)
    pl32<0>(v);                                               // S0=3
    pl16<1>(v);                                               // S1=1
    gate4<0, 1>(v, Mm);                                       // (3,1)
    LOADM(4);
    // L3: (5,1)                                       P=(4,0,6,2,7,5)
    pl32<0>(v);                                               // S0=5
    gate4<0, 1>(v, Mm);                                       // (5,1)

    // ---- expvals: bit 5 (wire 2) at slot 0, bit 1 (wire 6) at slot 1 ----
    float acc[6];
    {
        const float2 a = v[0], b = v[1], c = v[2], d = v[3];
        acc[0] = (a.x * b.x + a.y * b.y) + (c.x * d.x + c.y * d.y);
        acc[1] = (a.x * b.y - a.y * b.x) + (c.x * d.y - c.y * d.x);
        acc[2] = (a.x * a.x + a.y * a.y) - (b.x * b.x + b.y * b.y)
               + (c.x * c.x + c.y * c.y) - (d.x * d.x + d.y * d.y);
        acc[3] = (a.x * c.x + a.y * c.y) + (b.x * d.x + b.y * d.y);
        acc[4] = (a.x * c.y - a.y * c.x) + (b.x * d.y - b.y * d.x);
        acc[5] = (a.x * a.x + a.y * a.y) - (c.x * c.x + c.y * c.y)
               + (b.x * b.x + b.y * b.y) - (d.x * d.x + d.y * d.y);
    }
    acc[0] *= 2.f; acc[1] *= 2.f; acc[3] *= 2.f; acc[4] *= 2.f;
#pragma unroll
    for (int k = 0; k < 6; ++k) {
#pragma unroll
        for (int off = 32; off; off >>= 1) acc[k] += __shfl_xor(acc[k], off, 64);
    }
    if (lane == 0) {
        float* o = out + e * 6;
        o[0] = acc[0]; o[1] = acc[1]; o[2] = acc[2];
        o[3] = acc[3]; o[4] = acc[4]; o[5] = acc[5];
    }
}

extern "C" void kernel_launch(void* const* d_in, const int* in_sizes, int n_in,
                              void* d_out, int out_size, void* d_ws, size_t ws_size,
                              hipStream_t stream) {
    const float* x = (const float*)d_in[0];
    const float* w = (const float*)d_in[1];
    float* out = (float*)d_out;
    const int B = in_sizes[0] / DIM;  // 32768

    hipLaunchKernelGGL(qsvdd_setup, dim3(1), dim3(64), 0, stream, w);
    hipLaunchKernelGGL(qsvdd_main, dim3(B / 4), dim3(256), 0, stream, x, out);
}